// Round 1
// 957.806 us; speedup vs baseline: 11.2935x; 11.2935x over previous
//
#include <hip/hip_runtime.h>
#include <hip/hip_bf16.h>

typedef unsigned int u32;
typedef short bf16x8 __attribute__((ext_vector_type(8)));
typedef float floatx4 __attribute__((ext_vector_type(4)));

#define NNODES 50000
#define NEDGES 800000
#define INSZ   1024
#define EMB    500
#define EMBP   512

__device__ __forceinline__ short f2bf(float f) {
    u32 u = __builtin_bit_cast(u32, f);
    u32 r = u + 0x7FFFu + ((u >> 16) & 1u);   // round-to-nearest-even
    return (short)(r >> 16);
}
__device__ __forceinline__ float bf2f(short h) {
    u32 u = ((u32)(unsigned short)h) << 16;
    return __builtin_bit_cast(float, u);
}

#define GLDS16(gp, lp) __builtin_amdgcn_global_load_lds( \
    (const __attribute__((address_space(1))) u32*)(gp),  \
    (__attribute__((address_space(3))) u32*)(lp), 16, 0, 0)

// ---------------------------------------------------------------------------
// Pack fp32 weights -> zero-padded bf16 BT-layout operands.
//   wencP [512][1024] : wenc rows (pad m>=500)
//   Wmid  [512][1024] : k<512 -> conv^T (conv[k][m]), k>=512 -> lin[m][k-512]
//   wdecP [1024][512] : wdec K-padded
// grid covers 524288 threads.
// ---------------------------------------------------------------------------
__global__ void pack_all(const float* __restrict__ wenc, const float* __restrict__ conv,
                         const float* __restrict__ lin,  const float* __restrict__ wdec,
                         short* __restrict__ wencP, short* __restrict__ Wmid,
                         short* __restrict__ wdecP) {
    int tid = blockIdx.x * 256 + threadIdx.x;
    {   // wencP [512][1024]
        int m = tid >> 10, k = tid & 1023;
        wencP[tid] = (m < EMB) ? f2bf(wenc[m * INSZ + k]) : (short)0;
    }
    {   // Wmid [512][1024]
        int m = tid >> 10, k = tid & 1023;
        short v = 0;
        if (m < EMB) {
            if (k < EMBP) { if (k < EMB) v = f2bf(conv[k * EMB + m]); }
            else          { int kk = k - EMBP; if (kk < EMB) v = f2bf(lin[m * EMB + kk]); }
        }
        Wmid[tid] = v;
    }
    {   // wdecP [1024][512]
        int m = tid >> 9, k = tid & 511;
        wdecP[tid] = (k < EMB) ? f2bf(wdec[m * EMB + k]) : (short)0;
    }
}

// ---------------------------------------------------------------------------
// m97-pattern 128x128 MFMA GEMM bodies. 256 thr = 4 waves (2x2 of 64x64),
// BK=32. A-side staging varies per kernel; B staged with global_load_lds.
// C/D layout: col=lane&15, row=(lane>>4)*4+reg.
// ---------------------------------------------------------------------------

// ---- encoder: h[n,m] = sigmoid( sum_k x[n,k]*wencP[m,k] + benc[m] ) -------
__global__ __launch_bounds__(256)
void gemm_enc(const float* __restrict__ X, const short* __restrict__ Wp,
              const float* __restrict__ benc, short* __restrict__ H) {
    __shared__ short As[128 * 32];
    __shared__ short Bs[128 * 32];
    const int tid  = threadIdx.x;
    const int lane = tid & 63;
    const int wave = tid >> 6;
    const int wr   = (wave >> 1) * 64;
    const int wc   = (wave & 1) * 64;
    const int rowBase = blockIdx.y * 128;
    const int colBase = blockIdx.x * 128;

    floatx4 acc[4][4] = {};

    const int r0 = tid >> 2;
    const int c0 = (tid & 3) * 8;
    int ar0 = rowBase + r0;       if (ar0 >= NNODES) ar0 = NNODES - 1;
    int ar1 = rowBase + r0 + 64;  if (ar1 >= NNODES) ar1 = NNODES - 1;
    const float* xP0 = X + (size_t)ar0 * INSZ + c0;
    const float* xP1 = X + (size_t)ar1 * INSZ + c0;
    const short* bP0 = Wp + (size_t)(colBase + r0) * INSZ + c0;
    const short* bP1 = Wp + (size_t)(colBase + r0 + 64) * INSZ + c0;

    const int q8  = (lane >> 4) * 8;
    const int m16 = lane & 15;

    for (int k0 = 0; k0 < INSZ; k0 += 32) {
        {   // fp32 -> bf16 convert-on-stage for A
            floatx4 fa = *(const floatx4*)(xP0 + k0);
            floatx4 fb = *(const floatx4*)(xP0 + k0 + 4);
            floatx4 fc = *(const floatx4*)(xP1 + k0);
            floatx4 fd = *(const floatx4*)(xP1 + k0 + 4);
            bf16x8 p0, p1;
#pragma unroll
            for (int j = 0; j < 4; ++j) {
                p0[j] = f2bf(fa[j]); p0[4 + j] = f2bf(fb[j]);
                p1[j] = f2bf(fc[j]); p1[4 + j] = f2bf(fd[j]);
            }
            *(bf16x8*)&As[tid * 8] = p0;
            *(bf16x8*)&As[2048 + tid * 8] = p1;
        }
        GLDS16(bP0 + k0, &Bs[tid * 8]);
        GLDS16(bP1 + k0, &Bs[2048 + tid * 8]);
        __syncthreads();

        bf16x8 af[4], bfr[4];
#pragma unroll
        for (int i = 0; i < 4; ++i) {
            af[i]  = *(const bf16x8*)&As[(wr + i * 16 + m16) * 32 + q8];
            bfr[i] = *(const bf16x8*)&Bs[(wc + i * 16 + m16) * 32 + q8];
        }
#pragma unroll
        for (int i = 0; i < 4; ++i)
#pragma unroll
            for (int j = 0; j < 4; ++j)
                acc[i][j] = __builtin_amdgcn_mfma_f32_16x16x32_bf16(af[i], bfr[j], acc[i][j], 0, 0, 0);
        __syncthreads();
    }

    const int rq = (lane >> 4) * 4;
#pragma unroll
    for (int i = 0; i < 4; ++i)
#pragma unroll
        for (int j = 0; j < 4; ++j)
#pragma unroll
            for (int reg = 0; reg < 4; ++reg) {
                int row = rowBase + wr + i * 16 + rq + reg;
                int col = colBase + wc + j * 16 + m16;
                if (row < NNODES) {
                    float b = (col < EMB) ? benc[col] : 0.f;
                    float v = 1.f / (1.f + __expf(-(acc[i][j][reg] + b)));
                    H[(size_t)row * EMBP + col] = f2bf(v);
                }
            }
}

// ---- mid: hout[n,m] = sum_{k<512} agg[n,k]*Wmid[m,k]
//                     + sum_{k<512} h[n,k]*Wmid[m,512+k] -----------------
__global__ __launch_bounds__(256)
void gemm_mid(const float* __restrict__ Agg, const short* __restrict__ H,
              const short* __restrict__ Wm, short* __restrict__ Hout) {
    __shared__ short As[128 * 32];
    __shared__ short Bs[128 * 32];
    const int tid  = threadIdx.x;
    const int lane = tid & 63;
    const int wave = tid >> 6;
    const int wr   = (wave >> 1) * 64;
    const int wc   = (wave & 1) * 64;
    const int rowBase = blockIdx.y * 128;
    const int colBase = blockIdx.x * 128;

    floatx4 acc[4][4] = {};

    const int r0 = tid >> 2;
    const int c0 = (tid & 3) * 8;
    int ar0 = rowBase + r0;       if (ar0 >= NNODES) ar0 = NNODES - 1;
    int ar1 = rowBase + r0 + 64;  if (ar1 >= NNODES) ar1 = NNODES - 1;
    const float* agP0 = Agg + (size_t)ar0 * EMBP + c0;
    const float* agP1 = Agg + (size_t)ar1 * EMBP + c0;
    const short* hP0  = H + (size_t)ar0 * EMBP + c0;
    const short* hP1  = H + (size_t)ar1 * EMBP + c0;
    const short* wP0  = Wm + (size_t)(colBase + r0) * 1024 + c0;
    const short* wP1  = Wm + (size_t)(colBase + r0 + 64) * 1024 + c0;

    const int q8  = (lane >> 4) * 8;
    const int m16 = lane & 15;

    for (int k0 = 0; k0 < 1024; k0 += 32) {
        if (k0 < 512) {
            floatx4 fa = *(const floatx4*)(agP0 + k0);
            floatx4 fb = *(const floatx4*)(agP0 + k0 + 4);
            floatx4 fc = *(const floatx4*)(agP1 + k0);
            floatx4 fd = *(const floatx4*)(agP1 + k0 + 4);
            bf16x8 p0, p1;
#pragma unroll
            for (int j = 0; j < 4; ++j) {
                p0[j] = f2bf(fa[j]); p0[4 + j] = f2bf(fb[j]);
                p1[j] = f2bf(fc[j]); p1[4 + j] = f2bf(fd[j]);
            }
            *(bf16x8*)&As[tid * 8] = p0;
            *(bf16x8*)&As[2048 + tid * 8] = p1;
        } else {
            GLDS16(hP0 + (k0 - 512), &As[tid * 8]);
            GLDS16(hP1 + (k0 - 512), &As[2048 + tid * 8]);
        }
        GLDS16(wP0 + k0, &Bs[tid * 8]);
        GLDS16(wP1 + k0, &Bs[2048 + tid * 8]);
        __syncthreads();

        bf16x8 af[4], bfr[4];
#pragma unroll
        for (int i = 0; i < 4; ++i) {
            af[i]  = *(const bf16x8*)&As[(wr + i * 16 + m16) * 32 + q8];
            bfr[i] = *(const bf16x8*)&Bs[(wc + i * 16 + m16) * 32 + q8];
        }
#pragma unroll
        for (int i = 0; i < 4; ++i)
#pragma unroll
            for (int j = 0; j < 4; ++j)
                acc[i][j] = __builtin_amdgcn_mfma_f32_16x16x32_bf16(af[i], bfr[j], acc[i][j], 0, 0, 0);
        __syncthreads();
    }

    const int rq = (lane >> 4) * 4;
#pragma unroll
    for (int i = 0; i < 4; ++i)
#pragma unroll
        for (int j = 0; j < 4; ++j)
#pragma unroll
            for (int reg = 0; reg < 4; ++reg) {
                int row = rowBase + wr + i * 16 + rq + reg;
                int col = colBase + wc + j * 16 + m16;
                if (row < NNODES)
                    Hout[(size_t)row * EMBP + col] = f2bf(acc[i][j][reg]);
            }
}

// ---- decoder: out[n,m] = sum_k hout[n,k]*wdecP[m,k] + bdec[m], fp32 out --
__global__ __launch_bounds__(256)
void gemm_dec(const short* __restrict__ Hout, const short* __restrict__ Wd,
              const float* __restrict__ bdec, float* __restrict__ Out) {
    __shared__ short As[128 * 32];
    __shared__ short Bs[128 * 32];
    const int tid  = threadIdx.x;
    const int lane = tid & 63;
    const int wave = tid >> 6;
    const int wr   = (wave >> 1) * 64;
    const int wc   = (wave & 1) * 64;
    const int rowBase = blockIdx.y * 128;
    const int colBase = blockIdx.x * 128;

    floatx4 acc[4][4] = {};

    const int r0 = tid >> 2;
    const int c0 = (tid & 3) * 8;
    int ar0 = rowBase + r0;       if (ar0 >= NNODES) ar0 = NNODES - 1;
    int ar1 = rowBase + r0 + 64;  if (ar1 >= NNODES) ar1 = NNODES - 1;
    const short* aP0 = Hout + (size_t)ar0 * EMBP + c0;
    const short* aP1 = Hout + (size_t)ar1 * EMBP + c0;
    const short* bP0 = Wd + (size_t)(colBase + r0) * EMBP + c0;
    const short* bP1 = Wd + (size_t)(colBase + r0 + 64) * EMBP + c0;

    const int q8  = (lane >> 4) * 8;
    const int m16 = lane & 15;

    for (int k0 = 0; k0 < EMBP; k0 += 32) {
        GLDS16(aP0 + k0, &As[tid * 8]);
        GLDS16(aP1 + k0, &As[2048 + tid * 8]);
        GLDS16(bP0 + k0, &Bs[tid * 8]);
        GLDS16(bP1 + k0, &Bs[2048 + tid * 8]);
        __syncthreads();

        bf16x8 af[4], bfr[4];
#pragma unroll
        for (int i = 0; i < 4; ++i) {
            af[i]  = *(const bf16x8*)&As[(wr + i * 16 + m16) * 32 + q8];
            bfr[i] = *(const bf16x8*)&Bs[(wc + i * 16 + m16) * 32 + q8];
        }
#pragma unroll
        for (int i = 0; i < 4; ++i)
#pragma unroll
            for (int j = 0; j < 4; ++j)
                acc[i][j] = __builtin_amdgcn_mfma_f32_16x16x32_bf16(af[i], bfr[j], acc[i][j], 0, 0, 0);
        __syncthreads();
    }

    const int rq = (lane >> 4) * 4;
#pragma unroll
    for (int i = 0; i < 4; ++i)
#pragma unroll
        for (int j = 0; j < 4; ++j)
#pragma unroll
            for (int reg = 0; reg < 4; ++reg) {
                int row = rowBase + wr + i * 16 + rq + reg;
                int col = colBase + wc + j * 16 + m16;
                if (row < NNODES)
                    Out[(size_t)row * INSZ + col] = acc[i][j][reg] + bdec[col];
            }
}

// ---------------------------------------------------------------------------
// CSR-by-destination aggregation (replaces 4e8 fp32 global atomics, which
// were fabric-RMW-bound: WRITE_SIZE 12.5 GB = one 32B sector per atomic).
// ---------------------------------------------------------------------------

// 1) histogram of dst
__global__ __launch_bounds__(256)
void count_edges(const int* __restrict__ dst, int* __restrict__ counts) {
    int e = blockIdx.x * 256 + threadIdx.x;
    atomicAdd(&counts[dst[e]], 1);
}

// 2) exclusive prefix sum over counts[50000] -> rowPtr, cursor (single block)
__global__ __launch_bounds__(1024)
void scan_counts(const int* __restrict__ counts, int* __restrict__ rowPtr,
                 int* __restrict__ cursor) {
    __shared__ int wsum[16];
    __shared__ int sbase;
    const int t = threadIdx.x;
    const int lane = t & 63;
    const int wv = t >> 6;
    if (t == 0) sbase = 0;
    for (int chunk = 0; chunk < 50176; chunk += 1024) {   // 49 chunks of 1024
        int i = chunk + t;
        int c = (i < NNODES) ? counts[i] : 0;
        // wave-level inclusive scan (shfl, no barriers)
        int v = c;
#pragma unroll
        for (int off = 1; off < 64; off <<= 1) {
            int u = __shfl_up(v, off, 64);
            if (lane >= off) v += u;
        }
        if (lane == 63) wsum[wv] = v;
        __syncthreads();                       // wsum ready; sbase stable
        int woff = 0, total = 0;
#pragma unroll
        for (int w = 0; w < 16; ++w) {
            int s = wsum[w];
            if (w < wv) woff += s;
            total += s;
        }
        int base = sbase;
        __syncthreads();                       // all reads of sbase done
        if (i < NNODES) {
            int p = base + woff + v - c;       // exclusive prefix
            rowPtr[i] = p;
            cursor[i] = p;
        }
        if (t == 0) sbase = base + total;
        __syncthreads();                       // sbase/wsum safe for next chunk
    }
}

// 3) bucket-fill edges by destination
__global__ __launch_bounds__(256)
void fill_csr(const int* __restrict__ src, const int* __restrict__ dst,
              const float* __restrict__ ew, int* __restrict__ cursor,
              int* __restrict__ csrSrc, float* __restrict__ csrW) {
    int e = blockIdx.x * 256 + threadIdx.x;
    int d = dst[e];
    int p = atomicAdd(&cursor[d], 1);
    csrSrc[p] = src[e];
    csrW[p]   = ew[e];
}

// 4) gather: one wave per destination node; lane owns 8 of 512 cols.
//    agg[n] = sum_{e in in(n)} w_e * h[src_e]   (fp32 accum in regs,
//    single non-atomic row store; zero-count rows written as zeros, so
//    no agg memset is needed).
__global__ __launch_bounds__(256)
void aggregate(const short* __restrict__ H, const int* __restrict__ rowPtr,
               const int* __restrict__ counts, const int* __restrict__ csrSrc,
               const float* __restrict__ csrW, float* __restrict__ agg) {
    const int n    = blockIdx.x * 4 + (threadIdx.x >> 6);   // 12500*4 = 50000
    const int lane = threadIdx.x & 63;
    const int beg  = rowPtr[n];
    const int cnt  = counts[n];
    const short* hb = H + lane * 8;

    float acc[8] = {0.f, 0.f, 0.f, 0.f, 0.f, 0.f, 0.f, 0.f};
    int i = 0;
    for (; i + 2 <= cnt; i += 2) {              // 2x unroll: 2 loads in flight
        int   s0 = csrSrc[beg + i];
        int   s1 = csrSrc[beg + i + 1];
        float w0 = csrW[beg + i];
        float w1 = csrW[beg + i + 1];
        bf16x8 v0 = *(const bf16x8*)(hb + (size_t)s0 * EMBP);
        bf16x8 v1 = *(const bf16x8*)(hb + (size_t)s1 * EMBP);
#pragma unroll
        for (int j = 0; j < 8; ++j)
            acc[j] += w0 * bf2f(v0[j]) + w1 * bf2f(v1[j]);
    }
    if (i < cnt) {
        int   s0 = csrSrc[beg + i];
        float w0 = csrW[beg + i];
        bf16x8 v0 = *(const bf16x8*)(hb + (size_t)s0 * EMBP);
#pragma unroll
        for (int j = 0; j < 8; ++j)
            acc[j] += w0 * bf2f(v0[j]);
    }

    floatx4 o0, o1;
#pragma unroll
    for (int j = 0; j < 4; ++j) { o0[j] = acc[j]; o1[j] = acc[4 + j]; }
    float* ap = agg + (size_t)n * EMBP + lane * 8;
    *(floatx4*)ap       = o0;
    *(floatx4*)(ap + 4) = o1;
}

// ---------------------------------------------------------------------------
extern "C" void kernel_launch(void* const* d_in, const int* in_sizes, int n_in,
                              void* d_out, int out_size, void* d_ws, size_t ws_size,
                              hipStream_t stream) {
    // Reference dtypes: ALL float32 (+ int32 edge_index).
    const float* x    = (const float*)d_in[0];
    const int*   ei   = (const int*)d_in[1];
    const float* ew   = (const float*)d_in[2];
    const float* wenc = (const float*)d_in[3];
    const float* benc = (const float*)d_in[4];
    const float* wdec = (const float*)d_in[5];
    const float* bdec = (const float*)d_in[6];
    const float* conv = (const float*)d_in[7];
    const float* lin  = (const float*)d_in[8];
    float* out = (float*)d_out;   // [50000][1024] fp32 = 204.8 MB

    // ws: wencP 1MB | Wmid 1MB | wdecP 1MB | h 51.2MB | hout 51.2MB  (105.5MB)
    char* ws = (char*)d_ws;
    short* wencP = (short*)(ws);
    short* Wmid  = (short*)(ws + 1048576);
    short* wdecP = (short*)(ws + 2097152);
    short* h     = (short*)(ws + 3145728);
    short* hout  = (short*)(ws + 3145728 + 51200000);

    // agg fp32 [50000][512] = 102.4 MB in the FIRST HALF of d_out; fully
    // consumed by gemm_mid before gemm_dec overwrites d_out (stream order).
    float* agg = (float*)d_out;

    // CSR scratch lives in the SECOND HALF of d_out (dead until gemm_dec
    // overwrites all of d_out at the end): 7.0 MB of 102.4 MB available.
    char* scratch = (char*)d_out + 102400000;
    int*   counts = (int*)scratch;                 // 50000*4 = 200 KB
    int*   rowPtr = counts + NNODES;               // 200 KB
    int*   cursor = rowPtr + NNODES;               // 200 KB
    int*   csrSrc = cursor + NNODES;               // 3.2 MB
    float* csrW   = (float*)(csrSrc + NEDGES);     // 3.2 MB

    hipMemsetAsync(counts, 0, (size_t)NNODES * 4, stream);

    dim3 blk(256);
    pack_all<<<2048, blk, 0, stream>>>(wenc, conv, lin, wdec, wencP, Wmid, wdecP);

    int rowTiles = (NNODES + 127) / 128;   // 391

    // h = sigmoid(x @ wenc^T + benc)
    gemm_enc<<<dim3(EMBP / 128, rowTiles), blk, 0, stream>>>(x, wencP, benc, h);

    // CSR build: histogram -> scan -> bucket fill
    count_edges<<<NEDGES / 256, blk, 0, stream>>>(ei + NEDGES, counts);
    scan_counts<<<1, 1024, 0, stream>>>(counts, rowPtr, cursor);
    fill_csr<<<NEDGES / 256, blk, 0, stream>>>(ei, ei + NEDGES, ew, cursor, csrSrc, csrW);

    // agg[n] = sum_{in-edges} w * h[src]   (gather, no atomics)
    aggregate<<<NNODES / 4, blk, 0, stream>>>(h, rowPtr, counts, csrSrc, csrW, agg);

    // hout = agg @ conv + h @ lin^T   (mixed-A K=1024 against Wmid)
    gemm_mid<<<dim3(EMBP / 128, rowTiles), blk, 0, stream>>>(agg, h, Wmid, hout);

    // out = hout @ wdec^T + bdec      (fp32 store)
    gemm_dec<<<dim3(INSZ / 128, rowTiles), blk, 0, stream>>>(hout, wdecP, bdec, out);
}

// Round 2
// 930.125 us; speedup vs baseline: 11.6296x; 1.0298x over previous
//
#include <hip/hip_runtime.h>
#include <hip/hip_bf16.h>

typedef unsigned int u32;
typedef short bf16x8 __attribute__((ext_vector_type(8)));
typedef float floatx4 __attribute__((ext_vector_type(4)));

#define NNODES 50000
#define NEDGES 800000
#define INSZ   1024
#define EMB    500
#define EMBP   512

__device__ __forceinline__ short f2bf(float f) {
    u32 u = __builtin_bit_cast(u32, f);
    u32 r = u + 0x7FFFu + ((u >> 16) & 1u);   // round-to-nearest-even
    return (short)(r >> 16);
}
__device__ __forceinline__ float bf2f(short h) {
    u32 u = ((u32)(unsigned short)h) << 16;
    return __builtin_bit_cast(float, u);
}

#define GLDS16(gp, lp) __builtin_amdgcn_global_load_lds( \
    (const __attribute__((address_space(1))) u32*)(gp),  \
    (__attribute__((address_space(3))) u32*)(lp), 16, 0, 0)

// Bijective XCD-chunked swizzle (m204): hw block `orig` on XCD orig&7 gets
// the seq-th element of that XCD's contiguous chunk of the work space.
__device__ __forceinline__ u32 xcd_swz(u32 orig, u32 q, u32 r) {
    u32 xcd = orig & 7u, seq = orig >> 3;
    u32 base = (xcd < r) ? xcd * (q + 1u) : r * (q + 1u) + (xcd - r) * q;
    return base + seq;
}

// ---------------------------------------------------------------------------
// Pack fp32 weights -> zero-padded bf16 BT-layout operands.
// ---------------------------------------------------------------------------
__global__ void pack_all(const float* __restrict__ wenc, const float* __restrict__ conv,
                         const float* __restrict__ lin,  const float* __restrict__ wdec,
                         short* __restrict__ wencP, short* __restrict__ Wmid,
                         short* __restrict__ wdecP) {
    int tid = blockIdx.x * 256 + threadIdx.x;
    {   // wencP [512][1024]
        int m = tid >> 10, k = tid & 1023;
        wencP[tid] = (m < EMB) ? f2bf(wenc[m * INSZ + k]) : (short)0;
    }
    {   // Wmid [512][1024]
        int m = tid >> 10, k = tid & 1023;
        short v = 0;
        if (m < EMB) {
            if (k < EMBP) { if (k < EMB) v = f2bf(conv[k * EMB + m]); }
            else          { int kk = k - EMBP; if (kk < EMB) v = f2bf(lin[m * EMB + kk]); }
        }
        Wmid[tid] = v;
    }
    {   // wdecP [1024][512]
        int m = tid >> 9, k = tid & 511;
        wdecP[tid] = (k < EMB) ? f2bf(wdec[m * EMB + k]) : (short)0;
    }
}

// ---------------------------------------------------------------------------
// X fp32 -> bf16 once (numerically identical to the old convert-on-stage).
// 25000 blocks x 256 thr x 8 elems = 51.2M elems.
// ---------------------------------------------------------------------------
__global__ __launch_bounds__(256)
void conv_x(const float* __restrict__ X, short* __restrict__ Xb) {
    size_t base = ((size_t)blockIdx.x * 256 + threadIdx.x) * 8;
    floatx4 f0 = *(const floatx4*)(X + base);
    floatx4 f1 = *(const floatx4*)(X + base + 4);
    bf16x8 p;
#pragma unroll
    for (int j = 0; j < 4; ++j) { p[j] = f2bf(f0[j]); p[4 + j] = f2bf(f1[j]); }
    *(bf16x8*)(Xb + base) = p;
}

// ---------------------------------------------------------------------------
// Shared GEMM structure: 128x128 tile, 4 waves (2x2 of 64x64), BK=32,
// double-buffered LDS, prefetch-next-before-compute, ONE barrier per k-step.
// All operands bf16, staged with global_load_lds (width 16).
// C/D layout: col=lane&15, row=(lane>>4)*4+reg.
// ---------------------------------------------------------------------------

// ---- encoder: h[n,m] = sigmoid( sum_k xb[n,k]*wencP[m,k] + benc[m] ) ------
__global__ __launch_bounds__(256)
void gemm_enc(const short* __restrict__ Xb, const short* __restrict__ Wp,
              const float* __restrict__ benc, short* __restrict__ H) {
    __shared__ short As[2][128 * 32];
    __shared__ short Bs[2][128 * 32];
    const int tid  = threadIdx.x;
    const int lane = tid & 63;
    const int wave = tid >> 6;
    const int wr   = (wave >> 1) * 64;
    const int wc   = (wave & 1) * 64;
    const u32 swz  = xcd_swz(blockIdx.y * 4 + blockIdx.x, 195, 4);  // nwg=1564
    const int rowBase = (int)(swz >> 2) * 128;
    const int colBase = (int)(swz & 3) * 128;

    floatx4 acc[4][4] = {};

    const int r0 = tid >> 2;
    const int c0 = (tid & 3) * 8;
    int ar0 = rowBase + r0;       if (ar0 >= NNODES) ar0 = NNODES - 1;
    int ar1 = rowBase + r0 + 64;  if (ar1 >= NNODES) ar1 = NNODES - 1;
    const short* aP0 = Xb + (size_t)ar0 * INSZ + c0;
    const short* aP1 = Xb + (size_t)ar1 * INSZ + c0;
    const short* bP0 = Wp + (size_t)(colBase + r0) * INSZ + c0;
    const short* bP1 = Wp + (size_t)(colBase + r0 + 64) * INSZ + c0;

    const int q8  = (lane >> 4) * 8;
    const int m16 = lane & 15;

#define STAGE_E(buf, k0)                                   \
    GLDS16(aP0 + (k0), &As[buf][tid * 8]);                 \
    GLDS16(aP1 + (k0), &As[buf][2048 + tid * 8]);          \
    GLDS16(bP0 + (k0), &Bs[buf][tid * 8]);                 \
    GLDS16(bP1 + (k0), &Bs[buf][2048 + tid * 8]);

    STAGE_E(0, 0);
    __syncthreads();
    int cur = 0;
    for (int t = 0; t < 32; ++t) {
        if (t + 1 < 32) { STAGE_E(cur ^ 1, (t + 1) * 32); }
        bf16x8 af[4], bfr[4];
#pragma unroll
        for (int i = 0; i < 4; ++i) {
            af[i]  = *(const bf16x8*)&As[cur][(wr + i * 16 + m16) * 32 + q8];
            bfr[i] = *(const bf16x8*)&Bs[cur][(wc + i * 16 + m16) * 32 + q8];
        }
#pragma unroll
        for (int i = 0; i < 4; ++i)
#pragma unroll
            for (int j = 0; j < 4; ++j)
                acc[i][j] = __builtin_amdgcn_mfma_f32_16x16x32_bf16(af[i], bfr[j], acc[i][j], 0, 0, 0);
        __syncthreads();
        cur ^= 1;
    }
#undef STAGE_E

    const int rq = (lane >> 4) * 4;
#pragma unroll
    for (int i = 0; i < 4; ++i)
#pragma unroll
        for (int j = 0; j < 4; ++j)
#pragma unroll
            for (int reg = 0; reg < 4; ++reg) {
                int row = rowBase + wr + i * 16 + rq + reg;
                int col = colBase + wc + j * 16 + m16;
                if (row < NNODES) {
                    float b = (col < EMB) ? benc[col] : 0.f;
                    float v = 1.f / (1.f + __expf(-(acc[i][j][reg] + b)));
                    H[(size_t)row * EMBP + col] = f2bf(v);
                }
            }
}

// ---- mid: hout[n,m] = sum_{k<512} aggB[n,k]*Wmid[m,k]
//                     + sum_{k<512} h[n,k]*Wmid[m,512+k] -------------------
__global__ __launch_bounds__(256)
void gemm_mid(const short* __restrict__ AggB, const short* __restrict__ H,
              const short* __restrict__ Wm, short* __restrict__ Hout) {
    __shared__ short As[2][128 * 32];
    __shared__ short Bs[2][128 * 32];
    const int tid  = threadIdx.x;
    const int lane = tid & 63;
    const int wave = tid >> 6;
    const int wr   = (wave >> 1) * 64;
    const int wc   = (wave & 1) * 64;
    const u32 swz  = xcd_swz(blockIdx.y * 4 + blockIdx.x, 195, 4);  // nwg=1564
    const int rowBase = (int)(swz >> 2) * 128;
    const int colBase = (int)(swz & 3) * 128;

    floatx4 acc[4][4] = {};

    const int r0 = tid >> 2;
    const int c0 = (tid & 3) * 8;
    int ar0 = rowBase + r0;       if (ar0 >= NNODES) ar0 = NNODES - 1;
    int ar1 = rowBase + r0 + 64;  if (ar1 >= NNODES) ar1 = NNODES - 1;
    const short* agP0 = AggB + (size_t)ar0 * EMBP + c0;
    const short* agP1 = AggB + (size_t)ar1 * EMBP + c0;
    const short* hP0  = H + (size_t)ar0 * EMBP + c0;
    const short* hP1  = H + (size_t)ar1 * EMBP + c0;
    const short* wP0  = Wm + (size_t)(colBase + r0) * 1024 + c0;
    const short* wP1  = Wm + (size_t)(colBase + r0 + 64) * 1024 + c0;

    const int q8  = (lane >> 4) * 8;
    const int m16 = lane & 15;

#define STAGE_M(buf, k0)                                              \
    if ((k0) < 512) {                                                 \
        GLDS16(agP0 + (k0), &As[buf][tid * 8]);                       \
        GLDS16(agP1 + (k0), &As[buf][2048 + tid * 8]);                \
    } else {                                                          \
        GLDS16(hP0 + ((k0) - 512), &As[buf][tid * 8]);                \
        GLDS16(hP1 + ((k0) - 512), &As[buf][2048 + tid * 8]);         \
    }                                                                 \
    GLDS16(wP0 + (k0), &Bs[buf][tid * 8]);                            \
    GLDS16(wP1 + (k0), &Bs[buf][2048 + tid * 8]);

    STAGE_M(0, 0);
    __syncthreads();
    int cur = 0;
    for (int t = 0; t < 32; ++t) {
        if (t + 1 < 32) { STAGE_M(cur ^ 1, (t + 1) * 32); }
        bf16x8 af[4], bfr[4];
#pragma unroll
        for (int i = 0; i < 4; ++i) {
            af[i]  = *(const bf16x8*)&As[cur][(wr + i * 16 + m16) * 32 + q8];
            bfr[i] = *(const bf16x8*)&Bs[cur][(wc + i * 16 + m16) * 32 + q8];
        }
#pragma unroll
        for (int i = 0; i < 4; ++i)
#pragma unroll
            for (int j = 0; j < 4; ++j)
                acc[i][j] = __builtin_amdgcn_mfma_f32_16x16x32_bf16(af[i], bfr[j], acc[i][j], 0, 0, 0);
        __syncthreads();
        cur ^= 1;
    }
#undef STAGE_M

    const int rq = (lane >> 4) * 4;
#pragma unroll
    for (int i = 0; i < 4; ++i)
#pragma unroll
        for (int j = 0; j < 4; ++j)
#pragma unroll
            for (int reg = 0; reg < 4; ++reg) {
                int row = rowBase + wr + i * 16 + rq + reg;
                int col = colBase + wc + j * 16 + m16;
                if (row < NNODES)
                    Hout[(size_t)row * EMBP + col] = f2bf(acc[i][j][reg]);
            }
}

// ---- decoder: out[n,m] = sum_k hout[n,k]*wdecP[m,k] + bdec[m], fp32 out ---
__global__ __launch_bounds__(256)
void gemm_dec(const short* __restrict__ Hout, const short* __restrict__ Wd,
              const float* __restrict__ bdec, float* __restrict__ Out) {
    __shared__ short As[2][128 * 32];
    __shared__ short Bs[2][128 * 32];
    const int tid  = threadIdx.x;
    const int lane = tid & 63;
    const int wave = tid >> 6;
    const int wr   = (wave >> 1) * 64;
    const int wc   = (wave & 1) * 64;
    const u32 swz  = xcd_swz(blockIdx.y * 8 + blockIdx.x, 391, 0);  // nwg=3128
    const int rowBase = (int)(swz >> 3) * 128;
    const int colBase = (int)(swz & 7) * 128;

    floatx4 acc[4][4] = {};

    const int r0 = tid >> 2;
    const int c0 = (tid & 3) * 8;
    int ar0 = rowBase + r0;       if (ar0 >= NNODES) ar0 = NNODES - 1;
    int ar1 = rowBase + r0 + 64;  if (ar1 >= NNODES) ar1 = NNODES - 1;
    const short* aP0 = Hout + (size_t)ar0 * EMBP + c0;
    const short* aP1 = Hout + (size_t)ar1 * EMBP + c0;
    const short* bP0 = Wd + (size_t)(colBase + r0) * EMBP + c0;
    const short* bP1 = Wd + (size_t)(colBase + r0 + 64) * EMBP + c0;

    const int q8  = (lane >> 4) * 8;
    const int m16 = lane & 15;

#define STAGE_D(buf, k0)                                   \
    GLDS16(aP0 + (k0), &As[buf][tid * 8]);                 \
    GLDS16(aP1 + (k0), &As[buf][2048 + tid * 8]);          \
    GLDS16(bP0 + (k0), &Bs[buf][tid * 8]);                 \
    GLDS16(bP1 + (k0), &Bs[buf][2048 + tid * 8]);

    STAGE_D(0, 0);
    __syncthreads();
    int cur = 0;
    for (int t = 0; t < 16; ++t) {
        if (t + 1 < 16) { STAGE_D(cur ^ 1, (t + 1) * 32); }
        bf16x8 af[4], bfr[4];
#pragma unroll
        for (int i = 0; i < 4; ++i) {
            af[i]  = *(const bf16x8*)&As[cur][(wr + i * 16 + m16) * 32 + q8];
            bfr[i] = *(const bf16x8*)&Bs[cur][(wc + i * 16 + m16) * 32 + q8];
        }
#pragma unroll
        for (int i = 0; i < 4; ++i)
#pragma unroll
            for (int j = 0; j < 4; ++j)
                acc[i][j] = __builtin_amdgcn_mfma_f32_16x16x32_bf16(af[i], bfr[j], acc[i][j], 0, 0, 0);
        __syncthreads();
        cur ^= 1;
    }
#undef STAGE_D

    const int rq = (lane >> 4) * 4;
#pragma unroll
    for (int i = 0; i < 4; ++i)
#pragma unroll
        for (int j = 0; j < 4; ++j)
#pragma unroll
            for (int reg = 0; reg < 4; ++reg) {
                int row = rowBase + wr + i * 16 + rq + reg;
                int col = colBase + wc + j * 16 + m16;
                if (row < NNODES)
                    Out[(size_t)row * INSZ + col] = acc[i][j][reg] + bdec[col];
            }
}

// ---------------------------------------------------------------------------
// CSR-by-destination aggregation.
// ---------------------------------------------------------------------------
__global__ __launch_bounds__(256)
void count_edges(const int* __restrict__ dst, int* __restrict__ counts) {
    int e = blockIdx.x * 256 + threadIdx.x;
    atomicAdd(&counts[dst[e]], 1);
}

__global__ __launch_bounds__(1024)
void scan_counts(const int* __restrict__ counts, int* __restrict__ rowPtr,
                 int* __restrict__ cursor) {
    __shared__ int wsum[16];
    __shared__ int sbase;
    const int t = threadIdx.x;
    const int lane = t & 63;
    const int wv = t >> 6;
    if (t == 0) sbase = 0;
    for (int chunk = 0; chunk < 50176; chunk += 1024) {
        int i = chunk + t;
        int c = (i < NNODES) ? counts[i] : 0;
        int v = c;
#pragma unroll
        for (int off = 1; off < 64; off <<= 1) {
            int u = __shfl_up(v, off, 64);
            if (lane >= off) v += u;
        }
        if (lane == 63) wsum[wv] = v;
        __syncthreads();
        int woff = 0, total = 0;
#pragma unroll
        for (int w = 0; w < 16; ++w) {
            int s = wsum[w];
            if (w < wv) woff += s;
            total += s;
        }
        int base = sbase;
        __syncthreads();
        if (i < NNODES) {
            int p = base + woff + v - c;
            rowPtr[i] = p;
            cursor[i] = p;
        }
        if (t == 0) sbase = base + total;
        __syncthreads();
    }
}

__global__ __launch_bounds__(256)
void fill_csr(const int* __restrict__ src, const int* __restrict__ dst,
              const float* __restrict__ ew, int* __restrict__ cursor,
              int* __restrict__ csrSrc, float* __restrict__ csrW) {
    int e = blockIdx.x * 256 + threadIdx.x;
    int d = dst[e];
    int p = atomicAdd(&cursor[d], 1);
    csrSrc[p] = src[e];
    csrW[p]   = ew[e];
}

// gather: one wave per destination node; lane owns 8 of 512 cols.
// Writes bf16 directly (identical to the old fp32-store + convert-on-stage).
__global__ __launch_bounds__(256)
void aggregate(const short* __restrict__ H, const int* __restrict__ rowPtr,
               const int* __restrict__ counts, const int* __restrict__ csrSrc,
               const float* __restrict__ csrW, short* __restrict__ aggB) {
    const int n    = blockIdx.x * 4 + (threadIdx.x >> 6);
    const int lane = threadIdx.x & 63;
    const int beg  = rowPtr[n];
    const int cnt  = counts[n];
    const short* hb = H + lane * 8;

    float acc[8] = {0.f, 0.f, 0.f, 0.f, 0.f, 0.f, 0.f, 0.f};
    int i = 0;
    for (; i + 4 <= cnt; i += 4) {              // 4 row-loads in flight
        int   s0 = csrSrc[beg + i],     s1 = csrSrc[beg + i + 1];
        int   s2 = csrSrc[beg + i + 2], s3 = csrSrc[beg + i + 3];
        float w0 = csrW[beg + i],       w1 = csrW[beg + i + 1];
        float w2 = csrW[beg + i + 2],   w3 = csrW[beg + i + 3];
        bf16x8 v0 = *(const bf16x8*)(hb + (size_t)s0 * EMBP);
        bf16x8 v1 = *(const bf16x8*)(hb + (size_t)s1 * EMBP);
        bf16x8 v2 = *(const bf16x8*)(hb + (size_t)s2 * EMBP);
        bf16x8 v3 = *(const bf16x8*)(hb + (size_t)s3 * EMBP);
#pragma unroll
        for (int j = 0; j < 8; ++j)
            acc[j] += w0 * bf2f(v0[j]) + w1 * bf2f(v1[j])
                    + w2 * bf2f(v2[j]) + w3 * bf2f(v3[j]);
    }
    for (; i < cnt; ++i) {
        int   s0 = csrSrc[beg + i];
        float w0 = csrW[beg + i];
        bf16x8 v0 = *(const bf16x8*)(hb + (size_t)s0 * EMBP);
#pragma unroll
        for (int j = 0; j < 8; ++j)
            acc[j] += w0 * bf2f(v0[j]);
    }

    bf16x8 o;
#pragma unroll
    for (int j = 0; j < 8; ++j) o[j] = f2bf(acc[j]);
    *(bf16x8*)(aggB + (size_t)n * EMBP + lane * 8) = o;
}

// ---------------------------------------------------------------------------
extern "C" void kernel_launch(void* const* d_in, const int* in_sizes, int n_in,
                              void* d_out, int out_size, void* d_ws, size_t ws_size,
                              hipStream_t stream) {
    const float* x    = (const float*)d_in[0];
    const int*   ei   = (const int*)d_in[1];
    const float* ew   = (const float*)d_in[2];
    const float* wenc = (const float*)d_in[3];
    const float* benc = (const float*)d_in[4];
    const float* wdec = (const float*)d_in[5];
    const float* bdec = (const float*)d_in[6];
    const float* conv = (const float*)d_in[7];
    const float* lin  = (const float*)d_in[8];
    float* out = (float*)d_out;   // [50000][1024] fp32 = 204.8 MB

    // ws: wencP 1MB | Wmid 1MB | wdecP 1MB | h 51.2MB | hout 51.2MB
    char* ws = (char*)d_ws;
    short* wencP = (short*)(ws);
    short* Wmid  = (short*)(ws + 1048576);
    short* wdecP = (short*)(ws + 2097152);
    short* h     = (short*)(ws + 3145728);
    short* hout  = (short*)(ws + 3145728 + 51200000);

    // d_out region plan (all dead before gemm_dec's final overwrite):
    //   [0, 51.2MB)        aggB bf16 [50000][512]   (aggregate -> gemm_mid)
    //   [102.4, 204.8MB)   Xbf bf16 [50000][1024]   (conv_x -> gemm_enc)
    //   [102.4, 109.4MB)   CSR scratch, built AFTER gemm_enc (overwrites Xbf)
    short* aggB = (short*)d_out;
    short* Xbf  = (short*)((char*)d_out + 102400000);
    char*  scratch = (char*)d_out + 102400000;
    int*   counts = (int*)scratch;
    int*   rowPtr = counts + NNODES;
    int*   cursor = rowPtr + NNODES;
    int*   csrSrc = cursor + NNODES;
    float* csrW   = (float*)(csrSrc + NEDGES);

    dim3 blk(256);
    pack_all<<<2048, blk, 0, stream>>>(wenc, conv, lin, wdec, wencP, Wmid, wdecP);
    conv_x<<<25000, blk, 0, stream>>>(x, Xbf);

    int rowTiles = (NNODES + 127) / 128;   // 391

    // h = sigmoid(xb @ wenc^T + benc)
    gemm_enc<<<dim3(EMBP / 128, rowTiles), blk, 0, stream>>>(Xbf, wencP, benc, h);

    // CSR build (overwrites dead Xbf region) -> gather
    hipMemsetAsync(counts, 0, (size_t)NNODES * 4, stream);
    count_edges<<<NEDGES / 256, blk, 0, stream>>>(ei + NEDGES, counts);
    scan_counts<<<1, 1024, 0, stream>>>(counts, rowPtr, cursor);
    fill_csr<<<NEDGES / 256, blk, 0, stream>>>(ei, ei + NEDGES, ew, cursor, csrSrc, csrW);
    aggregate<<<NNODES / 4, blk, 0, stream>>>(h, rowPtr, counts, csrSrc, csrW, aggB);

    // hout = aggB @ conv + h @ lin^T
    gemm_mid<<<dim3(EMBP / 128, rowTiles), blk, 0, stream>>>(aggB, h, Wmid, hout);

    // out = hout @ wdec^T + bdec      (fp32 store)
    gemm_dec<<<dim3(INSZ / 128, rowTiles), blk, 0, stream>>>(hout, wdecP, bdec, out);
}

// Round 3
// 917.525 us; speedup vs baseline: 11.7894x; 1.0137x over previous
//
#include <hip/hip_runtime.h>
#include <hip/hip_bf16.h>

typedef unsigned int u32;
typedef short bf16x8 __attribute__((ext_vector_type(8)));
typedef float floatx4 __attribute__((ext_vector_type(4)));

#define NNODES 50000
#define NEDGES 800000
#define INSZ   1024
#define EMB    500
#define EMBP   512

__device__ __forceinline__ short f2bf(float f) {
    u32 u = __builtin_bit_cast(u32, f);
    u32 r = u + 0x7FFFu + ((u >> 16) & 1u);   // round-to-nearest-even
    return (short)(r >> 16);
}
__device__ __forceinline__ float bf2f(short h) {
    u32 u = ((u32)(unsigned short)h) << 16;
    return __builtin_bit_cast(float, u);
}

#define GLDS16(gp, lp) __builtin_amdgcn_global_load_lds( \
    (const __attribute__((address_space(1))) u32*)(gp),  \
    (__attribute__((address_space(3))) u32*)(lp), 16, 0, 0)

// Bijective XCD-chunked swizzle (m204): hw block `orig` on XCD orig&7 gets
// the seq-th element of that XCD's contiguous chunk of the logical space.
__device__ __forceinline__ u32 xcd_swz(u32 orig, u32 q, u32 r) {
    u32 xcd = orig & 7u, seq = orig >> 3;
    u32 base = (xcd < r) ? xcd * (q + 1u) : r * (q + 1u) + (xcd - r) * q;
    return base + seq;
}

// ---------------------------------------------------------------------------
// Pack fp32 weights -> zero-padded bf16 BT-layout operands.
//   wencP [512][1024]  : wenc rows (pad m>=500)
//   wdecP [1024][512]  : wdec K-padded (A-operand of gemm_wpre)
//   Bw    [1024][512]  : kk<512 -> conv[kk][j]; kk>=512 -> lin[j][kk-512]
//                        (B-operand of gemm_wpre)
// grid covers 524288 threads.
// ---------------------------------------------------------------------------
__global__ void pack_all(const float* __restrict__ wenc, const float* __restrict__ conv,
                         const float* __restrict__ lin,  const float* __restrict__ wdec,
                         short* __restrict__ wencP, short* __restrict__ wdecP,
                         short* __restrict__ Bw) {
    int tid = blockIdx.x * 256 + threadIdx.x;
    {   // wencP [512][1024]
        int m = tid >> 10, k = tid & 1023;
        wencP[tid] = (m < EMB) ? f2bf(wenc[m * INSZ + k]) : (short)0;
    }
    {   // wdecP [1024][512]
        int m = tid >> 9, k = tid & 511;
        wdecP[tid] = (k < EMB) ? f2bf(wdec[m * EMB + k]) : (short)0;
    }
    {   // Bw [1024][512]
        int kk = tid >> 9, j = tid & 511;
        short v = 0;
        if (j < EMB) {
            if (kk < EMB)                          v = f2bf(conv[kk * EMB + j]);
            else if (kk >= 512 && kk - 512 < EMB)  v = f2bf(lin[j * EMB + (kk - 512)]);
        }
        Bw[tid] = v;
    }
}

// ---------------------------------------------------------------------------
// X fp32 -> bf16 once. 25000 blocks x 256 thr x 8 elems = 51.2M elems.
// ---------------------------------------------------------------------------
__global__ __launch_bounds__(256)
void conv_x(const float* __restrict__ X, short* __restrict__ Xb) {
    size_t base = ((size_t)blockIdx.x * 256 + threadIdx.x) * 8;
    floatx4 f0 = *(const floatx4*)(X + base);
    floatx4 f1 = *(const floatx4*)(X + base + 4);
    bf16x8 p;
#pragma unroll
    for (int j = 0; j < 4; ++j) { p[j] = f2bf(f0[j]); p[4 + j] = f2bf(f1[j]); }
    *(bf16x8*)(Xb + base) = p;
}

// ---------------------------------------------------------------------------
// Shared GEMM structure: 128x128 tile, 4 waves (2x2 of 64x64), BK=32,
// double-buffered LDS, prefetch-next-before-compute, ONE barrier per k-step.
// All operands bf16, staged with global_load_lds (width 16).
// C/D layout: col=lane&15, row=(lane>>4)*4+reg.
// ---------------------------------------------------------------------------

// ---- Wbig precompute: Wbig[m][kk] = sum_j wdecP[m][j] * Bw[kk][j] ---------
// (== conv@wdec^T for kk<512, lin^T-mixed for kk>=512). M=N=1024, K=512.
__global__ __launch_bounds__(256)
void gemm_wpre(const short* __restrict__ Ap, const short* __restrict__ Bp,
               short* __restrict__ Wbig) {
    __shared__ short As[2][128 * 32];
    __shared__ short Bs[2][128 * 32];
    const int tid  = threadIdx.x;
    const int lane = tid & 63;
    const int wave = tid >> 6;
    const int wr   = (wave >> 1) * 64;
    const int wc   = (wave & 1) * 64;
    const int rowBase = blockIdx.y * 128;
    const int colBase = blockIdx.x * 128;

    floatx4 acc[4][4] = {};

    const int r0 = tid >> 2;
    const int c0 = (tid & 3) * 8;
    const short* aP0 = Ap + (size_t)(rowBase + r0) * EMBP + c0;
    const short* aP1 = Ap + (size_t)(rowBase + r0 + 64) * EMBP + c0;
    const short* bP0 = Bp + (size_t)(colBase + r0) * EMBP + c0;
    const short* bP1 = Bp + (size_t)(colBase + r0 + 64) * EMBP + c0;

    const int q8  = (lane >> 4) * 8;
    const int m16 = lane & 15;

#define STAGE_W(buf, k0)                                   \
    GLDS16(aP0 + (k0), &As[buf][tid * 8]);                 \
    GLDS16(aP1 + (k0), &As[buf][2048 + tid * 8]);          \
    GLDS16(bP0 + (k0), &Bs[buf][tid * 8]);                 \
    GLDS16(bP1 + (k0), &Bs[buf][2048 + tid * 8]);

    STAGE_W(0, 0);
    __syncthreads();
    int cur = 0;
    for (int t = 0; t < 16; ++t) {
        if (t + 1 < 16) { STAGE_W(cur ^ 1, (t + 1) * 32); }
        bf16x8 af[4], bfr[4];
#pragma unroll
        for (int i = 0; i < 4; ++i) {
            af[i]  = *(const bf16x8*)&As[cur][(wr + i * 16 + m16) * 32 + q8];
            bfr[i] = *(const bf16x8*)&Bs[cur][(wc + i * 16 + m16) * 32 + q8];
        }
#pragma unroll
        for (int i = 0; i < 4; ++i)
#pragma unroll
            for (int j = 0; j < 4; ++j)
                acc[i][j] = __builtin_amdgcn_mfma_f32_16x16x32_bf16(af[i], bfr[j], acc[i][j], 0, 0, 0);
        __syncthreads();
        cur ^= 1;
    }
#undef STAGE_W

    const int rq = (lane >> 4) * 4;
#pragma unroll
    for (int i = 0; i < 4; ++i)
#pragma unroll
        for (int j = 0; j < 4; ++j)
#pragma unroll
            for (int reg = 0; reg < 4; ++reg) {
                int row = rowBase + wr + i * 16 + rq + reg;
                int col = colBase + wc + j * 16 + m16;
                Wbig[(size_t)row * 1024 + col] = f2bf(acc[i][j][reg]);
            }
}

// ---- encoder: h[n,m] = sigmoid( sum_k xb[n,k]*wencP[m,k] + benc[m] ) ------
__global__ __launch_bounds__(256)
void gemm_enc(const short* __restrict__ Xb, const short* __restrict__ Wp,
              const float* __restrict__ benc, short* __restrict__ H) {
    __shared__ short As[2][128 * 32];
    __shared__ short Bs[2][128 * 32];
    const int tid  = threadIdx.x;
    const int lane = tid & 63;
    const int wave = tid >> 6;
    const int wr   = (wave >> 1) * 64;
    const int wc   = (wave & 1) * 64;
    const u32 swz  = xcd_swz(blockIdx.y * 4 + blockIdx.x, 195, 4);  // nwg=1564
    const int rowBase = (int)(swz >> 2) * 128;
    const int colBase = (int)(swz & 3) * 128;

    floatx4 acc[4][4] = {};

    const int r0 = tid >> 2;
    const int c0 = (tid & 3) * 8;
    int ar0 = rowBase + r0;       if (ar0 >= NNODES) ar0 = NNODES - 1;
    int ar1 = rowBase + r0 + 64;  if (ar1 >= NNODES) ar1 = NNODES - 1;
    const short* aP0 = Xb + (size_t)ar0 * INSZ + c0;
    const short* aP1 = Xb + (size_t)ar1 * INSZ + c0;
    const short* bP0 = Wp + (size_t)(colBase + r0) * INSZ + c0;
    const short* bP1 = Wp + (size_t)(colBase + r0 + 64) * INSZ + c0;

    const int q8  = (lane >> 4) * 8;
    const int m16 = lane & 15;

#define STAGE_E(buf, k0)                                   \
    GLDS16(aP0 + (k0), &As[buf][tid * 8]);                 \
    GLDS16(aP1 + (k0), &As[buf][2048 + tid * 8]);          \
    GLDS16(bP0 + (k0), &Bs[buf][tid * 8]);                 \
    GLDS16(bP1 + (k0), &Bs[buf][2048 + tid * 8]);

    STAGE_E(0, 0);
    __syncthreads();
    int cur = 0;
    for (int t = 0; t < 32; ++t) {
        if (t + 1 < 32) { STAGE_E(cur ^ 1, (t + 1) * 32); }
        bf16x8 af[4], bfr[4];
#pragma unroll
        for (int i = 0; i < 4; ++i) {
            af[i]  = *(const bf16x8*)&As[cur][(wr + i * 16 + m16) * 32 + q8];
            bfr[i] = *(const bf16x8*)&Bs[cur][(wc + i * 16 + m16) * 32 + q8];
        }
#pragma unroll
        for (int i = 0; i < 4; ++i)
#pragma unroll
            for (int j = 0; j < 4; ++j)
                acc[i][j] = __builtin_amdgcn_mfma_f32_16x16x32_bf16(af[i], bfr[j], acc[i][j], 0, 0, 0);
        __syncthreads();
        cur ^= 1;
    }
#undef STAGE_E

    const int rq = (lane >> 4) * 4;
#pragma unroll
    for (int i = 0; i < 4; ++i)
#pragma unroll
        for (int j = 0; j < 4; ++j)
#pragma unroll
            for (int reg = 0; reg < 4; ++reg) {
                int row = rowBase + wr + i * 16 + rq + reg;
                int col = colBase + wc + j * 16 + m16;
                if (row < NNODES) {
                    float b = (col < EMB) ? benc[col] : 0.f;
                    float v = 1.f / (1.f + __expf(-(acc[i][j][reg] + b)));
                    H[(size_t)row * EMBP + col] = f2bf(v);
                }
            }
}

// ---- fused mid+dec: out[n,m] = sum_{k<512} aggB[n,k]*Wbig[m][k]
//                              + sum_{k<512} h[n,k]*Wbig[m][512+k] + bdec[m]
__global__ __launch_bounds__(256)
void gemm_fused(const short* __restrict__ AggB, const short* __restrict__ H,
                const short* __restrict__ Wb, const float* __restrict__ bdec,
                float* __restrict__ Out) {
    __shared__ short As[2][128 * 32];
    __shared__ short Bs[2][128 * 32];
    const int tid  = threadIdx.x;
    const int lane = tid & 63;
    const int wave = tid >> 6;
    const int wr   = (wave >> 1) * 64;
    const int wc   = (wave & 1) * 64;
    const u32 swz  = xcd_swz(blockIdx.y * 8 + blockIdx.x, 391, 0);  // nwg=3128
    const int rowBase = (int)(swz >> 3) * 128;
    const int colBase = (int)(swz & 7) * 128;

    floatx4 acc[4][4] = {};

    const int r0 = tid >> 2;
    const int c0 = (tid & 3) * 8;
    int ar0 = rowBase + r0;       if (ar0 >= NNODES) ar0 = NNODES - 1;
    int ar1 = rowBase + r0 + 64;  if (ar1 >= NNODES) ar1 = NNODES - 1;
    const short* agP0 = AggB + (size_t)ar0 * EMBP + c0;
    const short* agP1 = AggB + (size_t)ar1 * EMBP + c0;
    const short* hP0  = H + (size_t)ar0 * EMBP + c0;
    const short* hP1  = H + (size_t)ar1 * EMBP + c0;
    const short* wP0  = Wb + (size_t)(colBase + r0) * 1024 + c0;
    const short* wP1  = Wb + (size_t)(colBase + r0 + 64) * 1024 + c0;

    const int q8  = (lane >> 4) * 8;
    const int m16 = lane & 15;

#define STAGE_F(buf, k0)                                              \
    if ((k0) < 512) {                                                 \
        GLDS16(agP0 + (k0), &As[buf][tid * 8]);                       \
        GLDS16(agP1 + (k0), &As[buf][2048 + tid * 8]);                \
    } else {                                                          \
        GLDS16(hP0 + ((k0) - 512), &As[buf][tid * 8]);                \
        GLDS16(hP1 + ((k0) - 512), &As[buf][2048 + tid * 8]);         \
    }                                                                 \
    GLDS16(wP0 + (k0), &Bs[buf][tid * 8]);                            \
    GLDS16(wP1 + (k0), &Bs[buf][2048 + tid * 8]);

    STAGE_F(0, 0);
    __syncthreads();
    int cur = 0;
    for (int t = 0; t < 32; ++t) {
        if (t + 1 < 32) { STAGE_F(cur ^ 1, (t + 1) * 32); }
        bf16x8 af[4], bfr[4];
#pragma unroll
        for (int i = 0; i < 4; ++i) {
            af[i]  = *(const bf16x8*)&As[cur][(wr + i * 16 + m16) * 32 + q8];
            bfr[i] = *(const bf16x8*)&Bs[cur][(wc + i * 16 + m16) * 32 + q8];
        }
#pragma unroll
        for (int i = 0; i < 4; ++i)
#pragma unroll
            for (int j = 0; j < 4; ++j)
                acc[i][j] = __builtin_amdgcn_mfma_f32_16x16x32_bf16(af[i], bfr[j], acc[i][j], 0, 0, 0);
        __syncthreads();
        cur ^= 1;
    }
#undef STAGE_F

    const int rq = (lane >> 4) * 4;
#pragma unroll
    for (int i = 0; i < 4; ++i)
#pragma unroll
        for (int j = 0; j < 4; ++j)
#pragma unroll
            for (int reg = 0; reg < 4; ++reg) {
                int row = rowBase + wr + i * 16 + rq + reg;
                int col = colBase + wc + j * 16 + m16;
                if (row < NNODES)
                    Out[(size_t)row * INSZ + col] = acc[i][j][reg] + bdec[col];
            }
}

// ---------------------------------------------------------------------------
// CSR-by-destination aggregation.
// ---------------------------------------------------------------------------
__global__ __launch_bounds__(256)
void count_edges(const int* __restrict__ dst, int* __restrict__ counts) {
    int e = blockIdx.x * 256 + threadIdx.x;
    atomicAdd(&counts[dst[e]], 1);
}

__global__ __launch_bounds__(1024)
void scan_counts(const int* __restrict__ counts, int* __restrict__ rowPtr,
                 int* __restrict__ cursor) {
    __shared__ int wsum[16];
    __shared__ int sbase;
    const int t = threadIdx.x;
    const int lane = t & 63;
    const int wv = t >> 6;
    if (t == 0) sbase = 0;
    for (int chunk = 0; chunk < 50176; chunk += 1024) {
        int i = chunk + t;
        int c = (i < NNODES) ? counts[i] : 0;
        int v = c;
#pragma unroll
        for (int off = 1; off < 64; off <<= 1) {
            int u = __shfl_up(v, off, 64);
            if (lane >= off) v += u;
        }
        if (lane == 63) wsum[wv] = v;
        __syncthreads();
        int woff = 0, total = 0;
#pragma unroll
        for (int w = 0; w < 16; ++w) {
            int s = wsum[w];
            if (w < wv) woff += s;
            total += s;
        }
        int base = sbase;
        __syncthreads();
        if (i < NNODES) {
            int p = base + woff + v - c;
            rowPtr[i] = p;
            cursor[i] = p;
        }
        if (t == 0) sbase = base + total;
        __syncthreads();
    }
}

__global__ __launch_bounds__(256)
void fill_csr(const int* __restrict__ src, const int* __restrict__ dst,
              const float* __restrict__ ew, int* __restrict__ cursor,
              int* __restrict__ csrSrc, float* __restrict__ csrW) {
    int e = blockIdx.x * 256 + threadIdx.x;
    int d = dst[e];
    int p = atomicAdd(&cursor[d], 1);
    csrSrc[p] = src[e];
    csrW[p]   = ew[e];
}

// gather: one wave per destination node; lane owns 8 of 512 cols.
// 8-deep load pipeline (fully unrolled -> all register indices static).
__global__ __launch_bounds__(256)
void aggregate(const short* __restrict__ H, const int* __restrict__ rowPtr,
               const int* __restrict__ counts, const int* __restrict__ csrSrc,
               const float* __restrict__ csrW, short* __restrict__ aggB) {
    const int n    = blockIdx.x * 4 + (threadIdx.x >> 6);
    const int lane = threadIdx.x & 63;
    const int beg  = rowPtr[n];
    const int cnt  = counts[n];
    const short* hb = H + lane * 8;

    float acc[8] = {0.f, 0.f, 0.f, 0.f, 0.f, 0.f, 0.f, 0.f};
    int i = 0;
    for (; i + 8 <= cnt; i += 8) {
        int   s[8]; float w[8]; bf16x8 v[8];
#pragma unroll
        for (int u = 0; u < 8; ++u) { s[u] = csrSrc[beg + i + u]; w[u] = csrW[beg + i + u]; }
#pragma unroll
        for (int u = 0; u < 8; ++u) v[u] = *(const bf16x8*)(hb + (size_t)s[u] * EMBP);
#pragma unroll
        for (int u = 0; u < 8; ++u)
#pragma unroll
            for (int j = 0; j < 8; ++j)
                acc[j] += w[u] * bf2f(v[u][j]);
    }
    for (; i + 4 <= cnt; i += 4) {
        int   s[4]; float w[4]; bf16x8 v[4];
#pragma unroll
        for (int u = 0; u < 4; ++u) { s[u] = csrSrc[beg + i + u]; w[u] = csrW[beg + i + u]; }
#pragma unroll
        for (int u = 0; u < 4; ++u) v[u] = *(const bf16x8*)(hb + (size_t)s[u] * EMBP);
#pragma unroll
        for (int u = 0; u < 4; ++u)
#pragma unroll
            for (int j = 0; j < 8; ++j)
                acc[j] += w[u] * bf2f(v[u][j]);
    }
    for (; i < cnt; ++i) {
        int   s0 = csrSrc[beg + i];
        float w0 = csrW[beg + i];
        bf16x8 v0 = *(const bf16x8*)(hb + (size_t)s0 * EMBP);
#pragma unroll
        for (int j = 0; j < 8; ++j)
            acc[j] += w0 * bf2f(v0[j]);
    }

    bf16x8 o;
#pragma unroll
    for (int j = 0; j < 8; ++j) o[j] = f2bf(acc[j]);
    *(bf16x8*)(aggB + (size_t)n * EMBP + lane * 8) = o;
}

// ---------------------------------------------------------------------------
extern "C" void kernel_launch(void* const* d_in, const int* in_sizes, int n_in,
                              void* d_out, int out_size, void* d_ws, size_t ws_size,
                              hipStream_t stream) {
    const float* x    = (const float*)d_in[0];
    const int*   ei   = (const int*)d_in[1];
    const float* ew   = (const float*)d_in[2];
    const float* wenc = (const float*)d_in[3];
    const float* benc = (const float*)d_in[4];
    const float* wdec = (const float*)d_in[5];
    const float* bdec = (const float*)d_in[6];
    const float* conv = (const float*)d_in[7];
    const float* lin  = (const float*)d_in[8];
    float* out = (float*)d_out;   // [50000][1024] fp32 = 204.8 MB

    // ws layout (107.7 MB):
    //   0        wencP [512][1024]   1 MB
    //   1 MB     wdecP [1024][512]   1 MB
    //   2 MB     Bw    [1024][512]   1 MB
    //   3 MB     Wbig  [1024][1024]  2 MB
    //   5 MB     h     [50000][512]  51.2 MB
    //   56.2 MB  aggB  [50000][512]  51.2 MB   (bf16; must NOT alias d_out:
    //            gemm_fused reads it while writing all of d_out)
    char* ws = (char*)d_ws;
    short* wencP = (short*)(ws);
    short* wdecP = (short*)(ws + 1048576);
    short* Bw    = (short*)(ws + 2097152);
    short* Wbig  = (short*)(ws + 3145728);
    short* h     = (short*)(ws + 5242880);
    short* aggB  = (short*)(ws + 5242880 + 51200000);

    // d_out second half is dead until gemm_fused's final overwrite:
    //   [102.4MB, 204.8MB)  Xbf bf16 [50000][1024]  (conv_x -> gemm_enc)
    //   [102.4MB, 109.4MB)  CSR scratch, built AFTER gemm_enc (overwrites Xbf)
    short* Xbf  = (short*)((char*)d_out + 102400000);
    char*  scratch = (char*)d_out + 102400000;
    int*   counts = (int*)scratch;
    int*   rowPtr = counts + NNODES;
    int*   cursor = rowPtr + NNODES;
    int*   csrSrc = cursor + NNODES;
    float* csrW   = (float*)(csrSrc + NEDGES);

    dim3 blk(256);
    pack_all<<<2048, blk, 0, stream>>>(wenc, conv, lin, wdec, wencP, wdecP, Bw);

    // Wbig = wdec (x) [conv | lin^T]  (M=N=1024, K=512; 64 blocks)
    gemm_wpre<<<dim3(8, 8), blk, 0, stream>>>(wdecP, Bw, Wbig);

    conv_x<<<25000, blk, 0, stream>>>(x, Xbf);

    int rowTiles = (NNODES + 127) / 128;   // 391

    // h = sigmoid(xb @ wenc^T + benc)
    gemm_enc<<<dim3(EMBP / 128, rowTiles), blk, 0, stream>>>(Xbf, wencP, benc, h);

    // CSR build (overwrites dead Xbf region) -> gather
    hipMemsetAsync(counts, 0, (size_t)NNODES * 4, stream);
    count_edges<<<NEDGES / 256, blk, 0, stream>>>(ei + NEDGES, counts);
    scan_counts<<<1, 1024, 0, stream>>>(counts, rowPtr, cursor);
    fill_csr<<<NEDGES / 256, blk, 0, stream>>>(ei, ei + NEDGES, ew, cursor, csrSrc, csrW);
    aggregate<<<NNODES / 4, blk, 0, stream>>>(h, rowPtr, counts, csrSrc, csrW, aggB);

    // out = aggB @ Wbig[:, :512]^T + h @ Wbig[:, 512:]^T + bdec   (fused mid+dec)
    gemm_fused<<<dim3(INSZ / 128, rowTiles), blk, 0, stream>>>(aggB, h, Wbig, bdec, out);
}